// Round 3
// baseline (2654.033 us; speedup 1.0000x reference)
//
#include <hip/hip_runtime.h>

#define N_NODES 100000
#define N_EDGES 3200000
#define D 128

#define BSPAN 64                      // rows per bucket
#define NB 1563                       // ceil(N_NODES / BSPAN)
#define CAP 3072                      // record capacity per bucket (mean 2048)
#define PBLOCKS 256
#define PCHUNK (N_EDGES / PBLOCKS)    // 12500 edges per partition block
#define OVF_CAP 8192

// ws layout (bytes)
#define SUP_OFF     0ULL                       // bf16 support: 25,600,000
#define RECS_OFF    25600000ULL                // NB*CAP*8 = 38,412,288
#define TAILS_OFF   64012288ULL                // NB ints
#define OVFCNT_OFF  64018540ULL                // 1 int (contiguous with tails)
#define OVF_OFF     64018544ULL                // OVF_CAP * int3
#define WS_NEED     (OVF_OFF + (size_t)OVF_CAP * 12)

__device__ inline ushort f2bf(float f) {
  uint u = __float_as_uint(f);
  u += 0x7FFF + ((u >> 16) & 1);   // RNE
  return (ushort)(u >> 16);
}
__device__ inline float bf2f(ushort u) {
  return __uint_as_float(((uint)u) << 16);
}

// ---------------------------------------------------------------------------
// Kernel A: support(bf16) = x @ W + bias   (fp32 vector ALU, bf16 store)
// ---------------------------------------------------------------------------
__global__ __launch_bounds__(256) void gcn_gemm_kernel(
    const float* __restrict__ x, const float* __restrict__ W,
    const float* __restrict__ bias, ushort* __restrict__ support, int M) {
  __shared__ float Wl[D * D];
  __shared__ float Xl[32 * D];
  const int t = threadIdx.x;

  for (int i = t * 4; i < D * D; i += 256 * 4)
    *(float4*)&Wl[i] = *(const float4*)&W[i];
  const int row0 = blockIdx.x * 32;
  for (int i = t * 4; i < 32 * D; i += 256 * 4) {
    const int r = row0 + i / D;
    float4 v = make_float4(0.f, 0.f, 0.f, 0.f);
    if (r < M) v = *(const float4*)&x[(size_t)r * D + (i % D)];
    *(float4*)&Xl[i] = v;
  }
  __syncthreads();

  const int rbase = (t >> 5) * 4;
  const int cbase = (t & 31) * 4;
  float acc[4][4] = {};
  for (int k = 0; k < D; k += 4) {
    float4 xv[4];
#pragma unroll
    for (int i = 0; i < 4; i++) xv[i] = *(float4*)&Xl[(rbase + i) * D + k];
    float4 wv[4];
#pragma unroll
    for (int kk = 0; kk < 4; kk++) wv[kk] = *(float4*)&Wl[(k + kk) * D + cbase];
#pragma unroll
    for (int i = 0; i < 4; i++) {
      const float* xs = (const float*)&xv[i];
#pragma unroll
      for (int kk = 0; kk < 4; kk++) {
        acc[i][0] += xs[kk] * wv[kk].x;
        acc[i][1] += xs[kk] * wv[kk].y;
        acc[i][2] += xs[kk] * wv[kk].z;
        acc[i][3] += xs[kk] * wv[kk].w;
      }
    }
  }
  const float4 bv = *(const float4*)&bias[cbase];
#pragma unroll
  for (int i = 0; i < 4; i++) {
    const int r = row0 + rbase + i;
    if (r < M) {
      ushort4 o;
      o.x = f2bf(acc[i][0] + bv.x);
      o.y = f2bf(acc[i][1] + bv.y);
      o.z = f2bf(acc[i][2] + bv.z);
      o.w = f2bf(acc[i][3] + bv.w);
      *(ushort4*)&support[(size_t)r * D + cbase] = o;
    }
  }
}

// ---------------------------------------------------------------------------
// Partition: block-local binning -> contiguous per-block runs in row buckets.
// One global atomic per (block, non-empty bucket); record writes for a bucket
// come from one CU -> L2 line-merge (kills the 8x write amplification).
// ---------------------------------------------------------------------------
__global__ __launch_bounds__(256) void partition_kernel(
    const int* __restrict__ erow, const int* __restrict__ ecol,
    const float* __restrict__ eval, int* __restrict__ tails,
    int2* __restrict__ recs, int* __restrict__ ovf_cnt,
    int3* __restrict__ ovf) {
  __shared__ int cnt[NB];
  __shared__ int cursor[NB];
  const int t = threadIdx.x;
  for (int i = t; i < NB; i += 256) cnt[i] = 0;
  __syncthreads();

  const int e0 = blockIdx.x * PCHUNK;
  for (int e = e0 + t; e < e0 + PCHUNK; e += 256)
    atomicAdd(&cnt[erow[e] >> 6], 1);
  __syncthreads();

  for (int i = t; i < NB; i += 256) {
    const int c = cnt[i];
    cursor[i] = (c > 0) ? atomicAdd(&tails[i], c) : 0;
  }
  __syncthreads();

  for (int e = e0 + t; e < e0 + PCHUNK; e += 256) {
    const int row = erow[e];
    const int b = row >> 6;
    const int pos = atomicAdd(&cursor[b], 1);
    const int col = ecol[e];
    const int vb = __float_as_int(eval[e]);
    if (pos < CAP) {
      recs[(size_t)b * CAP + pos] = make_int2(col | ((row & 63) << 20), vb);
    } else {
      const int oi = atomicAdd(ovf_cnt, 1);
      if (oi < OVF_CAP) ovf[oi] = make_int3(row, col, vb);
    }
  }
}

// ---------------------------------------------------------------------------
// Gather: one block per bucket; 32 KB LDS fp32 accumulator (64 rows x 128).
// Records broadcast via v_readlane (SALU — keeps LDS pipe for ds_add_f32).
// Lane owns cols {l, l+64}: LDS atomics are 2-way bank-aliased (free).
// ---------------------------------------------------------------------------
__global__ __launch_bounds__(256) void gather_kernel(
    const ushort* __restrict__ sup, const int* __restrict__ tails,
    const int2* __restrict__ recs, float* __restrict__ out) {
  __shared__ float acc[BSPAN * D];   // 32 KB
  const int bi = blockIdx.x;
  const int t = threadIdx.x;
  for (int i = t * 4; i < BSPAN * D; i += 1024)
    *(float4*)&acc[i] = make_float4(0.f, 0.f, 0.f, 0.f);
  __syncthreads();

  const int n = min(tails[bi], CAP);
  const int2* rbase = recs + (size_t)bi * CAP;
  const int lane = t & 63;

  for (int base = (t >> 6) * 64; base < n; base += 256) {
    int2 rec = make_int2(0, 0);
    if (base + lane < n) rec = rbase[base + lane];
    const int m = min(64, n - base);
    if (m == 64) {
#pragma unroll
      for (int i = 0; i < 64; i++) {
        const int meta = __builtin_amdgcn_readlane(rec.x, i);
        const float val = __int_as_float(__builtin_amdgcn_readlane(rec.y, i));
        const int col = meta & 0xFFFFF;
        const int riB = meta >> 20;
        const float f0 = bf2f(sup[(size_t)col * D + lane]);
        const float f1 = bf2f(sup[(size_t)col * D + lane + 64]);
        atomicAdd(&acc[riB * D + lane], val * f0);
        atomicAdd(&acc[riB * D + lane + 64], val * f1);
      }
    } else {
      for (int i = 0; i < m; i++) {
        const int meta = __shfl(rec.x, i);
        const float val = __int_as_float(__shfl(rec.y, i));
        const int col = meta & 0xFFFFF;
        const int riB = meta >> 20;
        const float f0 = bf2f(sup[(size_t)col * D + lane]);
        const float f1 = bf2f(sup[(size_t)col * D + lane + 64]);
        atomicAdd(&acc[riB * D + lane], val * f0);
        atomicAdd(&acc[riB * D + lane + 64], val * f1);
      }
    }
  }
  __syncthreads();

  const int row0 = bi * BSPAN;
  for (int i = t * 4; i < BSPAN * D; i += 1024) {
    const int r = row0 + i / D;
    if (r < N_NODES)
      *(float4*)&out[(size_t)r * D + (i % D)] = *(float4*)&acc[i];
  }
}

// Overflow apply (expected n == 0; formal safety net). Runs AFTER gather.
__global__ __launch_bounds__(256) void ovf_apply(
    const int* __restrict__ ovf_cnt, const int3* __restrict__ ovf,
    const ushort* __restrict__ sup, float* __restrict__ out) {
  const int tid = blockIdx.x * 256 + threadIdx.x;
  const int e = tid >> 5;
  const int n = min(*ovf_cnt, OVF_CAP);
  if (e >= n) return;
  const int3 rec = ovf[e];
  const float val = __int_as_float(rec.z);
  const int j = (tid & 31) * 4;
#pragma unroll
  for (int k = 0; k < 4; k++) {
    const float f = bf2f(sup[(size_t)rec.y * D + j + k]);
    unsafeAtomicAdd(&out[(size_t)rec.x * D + j + k], val * f);
  }
}

// Fallback (atomic path, bf16 support) if ws is too small.
__global__ __launch_bounds__(256) void gcn_spmm_atomic(
    const ushort* __restrict__ sup, const float* __restrict__ edge_val,
    const int* __restrict__ edge_row, const int* __restrict__ edge_col,
    float* __restrict__ out) {
  const long long tid = (long long)blockIdx.x * blockDim.x + threadIdx.x;
  const int e = (int)(tid >> 5);
  if (e >= N_EDGES) return;
  const int j = ((int)tid & 31) * 4;
  const int col = edge_col[e];
  const int row = edge_row[e];
  const float val = edge_val[e];
#pragma unroll
  for (int k = 0; k < 4; k++) {
    const float f = bf2f(sup[(size_t)col * D + j + k]);
    unsafeAtomicAdd(&out[(size_t)row * D + j + k], val * f);
  }
}

extern "C" void kernel_launch(void* const* d_in, const int* in_sizes, int n_in,
                              void* d_out, int out_size, void* d_ws,
                              size_t ws_size, hipStream_t stream) {
  const float* x        = (const float*)d_in[0];
  const float* edge_val = (const float*)d_in[1];
  const float* W        = (const float*)d_in[2];
  const float* bias     = (const float*)d_in[3];
  const int*   edge_row = (const int*)d_in[4];
  const int*   edge_col = (const int*)d_in[5];
  float* out = (float*)d_out;

  char* ws = (char*)d_ws;
  ushort* support = (ushort*)(ws + SUP_OFF);

  const int gemm_blocks = (N_NODES + 31) / 32;
  gcn_gemm_kernel<<<gemm_blocks, 256, 0, stream>>>(x, W, bias, support, N_NODES);

  if (ws_size >= WS_NEED) {
    int2* recs   = (int2*)(ws + RECS_OFF);
    int*  tails  = (int*)(ws + TAILS_OFF);
    int*  ovfcnt = (int*)(ws + OVFCNT_OFF);
    int3* ovf    = (int3*)(ws + OVF_OFF);

    // zero tails + ovf counter (contiguous region)
    hipMemsetAsync(tails, 0, (OVFCNT_OFF - TAILS_OFF) + 4, stream);
    partition_kernel<<<PBLOCKS, 256, 0, stream>>>(edge_row, edge_col, edge_val,
                                                  tails, recs, ovfcnt, ovf);
    gather_kernel<<<NB, 256, 0, stream>>>(support, tails, recs, out);
    ovf_apply<<<OVF_CAP * 32 / 256, 256, 0, stream>>>(ovfcnt, ovf, support, out);
  } else {
    hipMemsetAsync(out, 0, (size_t)out_size * sizeof(float), stream);
    const long long spmm_threads = (long long)N_EDGES * 32;
    gcn_spmm_atomic<<<(int)((spmm_threads + 255) / 256), 256, 0, stream>>>(
        support, edge_val, edge_row, edge_col, out);
  }
}

// Round 4
// 472.837 us; speedup vs baseline: 5.6130x; 5.6130x over previous
//
#include <hip/hip_runtime.h>

#define N_NODES 100000
#define N_EDGES 3200000
#define D 128

#define BSPAN 64                      // rows per bucket
#define NB 1563                       // ceil(N_NODES / BSPAN)
#define CAP 2560                      // records per bucket (mean 2048, +11 sigma)
#define PBLOCKS 256
#define PCHUNK (N_EDGES / PBLOCKS)    // 12500 edges per partition block
#define OVF_CAP 8192

// ws layout (bytes)
#define SUP_OFF     0ULL                               // bf16 support: 25,600,000
#define RECS_OFF    25600000ULL                        // NB*CAP*8 = 32,010,240
#define TAILS_OFF   (RECS_OFF + (size_t)NB * CAP * 8)  // NB ints
#define OVFCNT_OFF  (TAILS_OFF + (size_t)NB * 4)       // 1 int (contiguous)
#define OVF_OFF     ((OVFCNT_OFF + 15) & ~15ULL)
#define WS_NEED     (OVF_OFF + (size_t)OVF_CAP * 12)

__device__ inline ushort f2bf(float f) {
  uint u = __float_as_uint(f);
  u += 0x7FFF + ((u >> 16) & 1);   // RNE
  return (ushort)(u >> 16);
}
__device__ inline float bf2f(ushort u) {
  return __uint_as_float(((uint)u) << 16);
}

// ---------------------------------------------------------------------------
// Kernel A: support(bf16) = x @ W + bias   (fp32 vector ALU, bf16 store)
// ---------------------------------------------------------------------------
__global__ __launch_bounds__(256) void gcn_gemm_kernel(
    const float* __restrict__ x, const float* __restrict__ W,
    const float* __restrict__ bias, ushort* __restrict__ support, int M) {
  __shared__ float Wl[D * D];
  __shared__ float Xl[32 * D];
  const int t = threadIdx.x;

  for (int i = t * 4; i < D * D; i += 256 * 4)
    *(float4*)&Wl[i] = *(const float4*)&W[i];
  const int row0 = blockIdx.x * 32;
  for (int i = t * 4; i < 32 * D; i += 256 * 4) {
    const int r = row0 + i / D;
    float4 v = make_float4(0.f, 0.f, 0.f, 0.f);
    if (r < M) v = *(const float4*)&x[(size_t)r * D + (i % D)];
    *(float4*)&Xl[i] = v;
  }
  __syncthreads();

  const int rbase = (t >> 5) * 4;
  const int cbase = (t & 31) * 4;
  float acc[4][4] = {};
  for (int k = 0; k < D; k += 4) {
    float4 xv[4];
#pragma unroll
    for (int i = 0; i < 4; i++) xv[i] = *(float4*)&Xl[(rbase + i) * D + k];
    float4 wv[4];
#pragma unroll
    for (int kk = 0; kk < 4; kk++) wv[kk] = *(float4*)&Wl[(k + kk) * D + cbase];
#pragma unroll
    for (int i = 0; i < 4; i++) {
      const float* xs = (const float*)&xv[i];
#pragma unroll
      for (int kk = 0; kk < 4; kk++) {
        acc[i][0] += xs[kk] * wv[kk].x;
        acc[i][1] += xs[kk] * wv[kk].y;
        acc[i][2] += xs[kk] * wv[kk].z;
        acc[i][3] += xs[kk] * wv[kk].w;
      }
    }
  }
  const float4 bv = *(const float4*)&bias[cbase];
#pragma unroll
  for (int i = 0; i < 4; i++) {
    const int r = row0 + rbase + i;
    if (r < M) {
      ushort4 o;
      o.x = f2bf(acc[i][0] + bv.x);
      o.y = f2bf(acc[i][1] + bv.y);
      o.z = f2bf(acc[i][2] + bv.z);
      o.w = f2bf(acc[i][3] + bv.w);
      *(ushort4*)&support[(size_t)r * D + cbase] = o;
    }
  }
}

// ---------------------------------------------------------------------------
// Partition: block-local binning -> contiguous per-block runs in row buckets.
// 1024 threads (16 waves/CU) for latency hiding; one global atomic per
// (block, bucket); record runs (~64 B) written by one CU -> L2 line-merge.
// ---------------------------------------------------------------------------
__global__ __launch_bounds__(1024) void partition_kernel(
    const int* __restrict__ erow, const int* __restrict__ ecol,
    const float* __restrict__ eval, int* __restrict__ tails,
    int2* __restrict__ recs, int* __restrict__ ovf_cnt,
    int3* __restrict__ ovf) {
  __shared__ int cnt[NB];
  __shared__ int cursor[NB];
  const int t = threadIdx.x;
  for (int i = t; i < NB; i += 1024) cnt[i] = 0;
  __syncthreads();

  const int e0 = blockIdx.x * PCHUNK;
  for (int e = e0 + t; e < e0 + PCHUNK; e += 1024)
    atomicAdd(&cnt[erow[e] >> 6], 1);
  __syncthreads();

  for (int i = t; i < NB; i += 1024) {
    const int c = cnt[i];
    cursor[i] = (c > 0) ? atomicAdd(&tails[i], c) : 0;
  }
  __syncthreads();

  for (int e = e0 + t; e < e0 + PCHUNK; e += 1024) {
    const int row = erow[e];
    const int b = row >> 6;
    const int pos = atomicAdd(&cursor[b], 1);
    const int col = ecol[e];
    const int vb = __float_as_int(eval[e]);
    if (pos < CAP) {
      recs[(size_t)b * CAP + pos] = make_int2(col | ((row & 63) << 20), vb);
    } else {
      const int oi = atomicAdd(ovf_cnt, 1);
      if (oi < OVF_CAP) ovf[oi] = make_int3(row, col, vb);
    }
  }
}

// ---------------------------------------------------------------------------
// Fused bin+gather: block = one 64-row bucket.
//  1) bin the bucket's records into per-row order in LDS (count/scan/rank)
//  2) wave w gathers rows w*16..w*16+15 with REGISTER float2 accumulators;
//     records broadcast via same-address ds_read_b64 (conflict-free);
//     support read as one uint/lane (2 bf16) -> 256 B coalesced per record
//  3) each 512 B out row written exactly once
// ---------------------------------------------------------------------------
__global__ __launch_bounds__(256) void bucket_gather(
    const ushort* __restrict__ sup, const int* __restrict__ tails,
    const int2* __restrict__ recs, float* __restrict__ out) {
  __shared__ int2 lrec[CAP];            // 20 KB
  __shared__ int rcnt[BSPAN];
  __shared__ int rstart[BSPAN];
  __shared__ int rend[BSPAN];
  __shared__ int rpos[BSPAN];

  const int bi = blockIdx.x;
  const int t = threadIdx.x;
  const int n = min(tails[bi], CAP);
  const int2* __restrict__ gbase = recs + (size_t)bi * CAP;

  if (t < BSPAN) rcnt[t] = 0;
  __syncthreads();

  // pass 1: count per local row
  for (int i = t; i < n; i += 256)
    atomicAdd(&rcnt[gbase[i].x >> 20], 1);
  __syncthreads();

  // wave 0: inclusive shfl-scan over 64 counts
  if (t < 64) {
    const int c = rcnt[t];
    int v = c;
#pragma unroll
    for (int off = 1; off < 64; off <<= 1) {
      const int u = __shfl_up(v, off);
      if (t >= off) v += u;
    }
    rend[t] = v;
    rstart[t] = v - c;
    rpos[t] = v - c;
  }
  __syncthreads();

  // pass 2: rank + place into per-row order (records re-read; L2-hot)
  for (int i = t; i < n; i += 256) {
    const int2 rc = gbase[i];
    const int r = rc.x >> 20;
    const int p = atomicAdd(&rpos[r], 1);
    lrec[p] = make_int2(rc.x & 0xFFFFF, rc.y);
  }
  __syncthreads();

  // gather: wave (t>>6) owns 16 rows; register accumulators
  const int lane = t & 63;
  const int w = t >> 6;
  for (int j = 0; j < 16; j++) {
    const int rr = w * 16 + j;
    const int s = rstart[rr];
    const int e = rend[rr];
    float2 acc = make_float2(0.f, 0.f);
    for (int i = s; i < e; i++) {
      const int2 rc = lrec[i];                 // broadcast, conflict-free
      const float val = __int_as_float(rc.y);
      const uint b = *(const uint*)&sup[(size_t)rc.x * D + lane * 2];
      acc.x += val * bf2f((ushort)(b & 0xFFFF));
      acc.y += val * bf2f((ushort)(b >> 16));
    }
    const int row = bi * BSPAN + rr;
    if (row < N_NODES)
      *(float2*)&out[(size_t)row * D + lane * 2] = acc;
  }
}

// Overflow apply (expected n == 0; formal safety net). Runs AFTER gather.
__global__ __launch_bounds__(256) void ovf_apply(
    const int* __restrict__ ovf_cnt, const int3* __restrict__ ovf,
    const ushort* __restrict__ sup, float* __restrict__ out) {
  const int tid = blockIdx.x * 256 + threadIdx.x;
  const int e = tid >> 5;
  const int n = min(*ovf_cnt, OVF_CAP);
  if (e >= n) return;
  const int3 rec = ovf[e];
  const float val = __int_as_float(rec.z);
  const int j = (tid & 31) * 4;
#pragma unroll
  for (int k = 0; k < 4; k++) {
    const float f = bf2f(sup[(size_t)rec.y * D + j + k]);
    unsafeAtomicAdd(&out[(size_t)rec.x * D + j + k], val * f);
  }
}

// Fallback (atomic path, bf16 support) if ws is too small.
__global__ __launch_bounds__(256) void gcn_spmm_atomic(
    const ushort* __restrict__ sup, const float* __restrict__ edge_val,
    const int* __restrict__ edge_row, const int* __restrict__ edge_col,
    float* __restrict__ out) {
  const long long tid = (long long)blockIdx.x * blockDim.x + threadIdx.x;
  const int e = (int)(tid >> 5);
  if (e >= N_EDGES) return;
  const int j = ((int)tid & 31) * 4;
  const int col = edge_col[e];
  const int row = edge_row[e];
  const float val = edge_val[e];
#pragma unroll
  for (int k = 0; k < 4; k++) {
    const float f = bf2f(sup[(size_t)col * D + j + k]);
    unsafeAtomicAdd(&out[(size_t)row * D + j + k], val * f);
  }
}

extern "C" void kernel_launch(void* const* d_in, const int* in_sizes, int n_in,
                              void* d_out, int out_size, void* d_ws,
                              size_t ws_size, hipStream_t stream) {
  const float* x        = (const float*)d_in[0];
  const float* edge_val = (const float*)d_in[1];
  const float* W        = (const float*)d_in[2];
  const float* bias     = (const float*)d_in[3];
  const int*   edge_row = (const int*)d_in[4];
  const int*   edge_col = (const int*)d_in[5];
  float* out = (float*)d_out;

  char* ws = (char*)d_ws;
  ushort* support = (ushort*)(ws + SUP_OFF);

  const int gemm_blocks = (N_NODES + 31) / 32;
  gcn_gemm_kernel<<<gemm_blocks, 256, 0, stream>>>(x, W, bias, support, N_NODES);

  if (ws_size >= WS_NEED) {
    int2* recs   = (int2*)(ws + RECS_OFF);
    int*  tails  = (int*)(ws + TAILS_OFF);
    int*  ovfcnt = (int*)(ws + OVFCNT_OFF);
    int3* ovf    = (int3*)(ws + OVF_OFF);

    // zero tails + ovf counter (contiguous region)
    hipMemsetAsync(tails, 0, (size_t)NB * 4 + 4, stream);
    partition_kernel<<<PBLOCKS, 1024, 0, stream>>>(edge_row, edge_col, edge_val,
                                                   tails, recs, ovfcnt, ovf);
    bucket_gather<<<NB, 256, 0, stream>>>(support, tails, recs, out);
    ovf_apply<<<OVF_CAP * 32 / 256, 256, 0, stream>>>(ovfcnt, ovf, support, out);
  } else {
    hipMemsetAsync(out, 0, (size_t)out_size * sizeof(float), stream);
    const long long spmm_threads = (long long)N_EDGES * 32;
    gcn_spmm_atomic<<<(int)((spmm_threads + 255) / 256), 256, 0, stream>>>(
        support, edge_val, edge_row, edge_col, out);
  }
}

// Round 5
// 355.998 us; speedup vs baseline: 7.4552x; 1.3282x over previous
//
#include <hip/hip_runtime.h>

#define N_NODES 100000
#define N_EDGES 3200000
#define D 128

#define BSPAN 64                      // rows per bucket
#define NB 1563                       // ceil(N_NODES / BSPAN)
#define CAP 2560                      // records per bucket (mean 2048, +11 sigma)
#define PBLOCKS 256
#define PCHUNK (N_EDGES / PBLOCKS)    // 12500 edges per partition block
#define OVF_CAP 8192

// ws layout (bytes)
#define SUP_OFF     0ULL                               // bf16 support: 25,600,000
#define RECS_OFF    25600000ULL                        // NB*CAP*8 = 32,010,240
#define TAILS_OFF   (RECS_OFF + (size_t)NB * CAP * 8)  // NB ints
#define OVFCNT_OFF  (TAILS_OFF + (size_t)NB * 4)       // 1 int (contiguous)
#define OVF_OFF     ((OVFCNT_OFF + 15) & ~15ULL)
#define WS_NEED     (OVF_OFF + (size_t)OVF_CAP * 12)

typedef short short8 __attribute__((ext_vector_type(8)));
typedef float floatx4 __attribute__((ext_vector_type(4)));
typedef unsigned short ushort8v __attribute__((ext_vector_type(8)));

__device__ inline ushort f2bf(float f) {
  uint u = __float_as_uint(f);
  u += 0x7FFF + ((u >> 16) & 1);   // RNE
  return (ushort)(u >> 16);
}
__device__ inline float bf_lo(uint b) { return __uint_as_float(b << 16); }
__device__ inline float bf_hi(uint b) { return __uint_as_float(b & 0xFFFF0000u); }

// ---------------------------------------------------------------------------
// Kernel A: support(bf16) = x @ W + bias via MFMA 16x16x32 bf16.
// Block = 256 thr = 4 waves; 64-row M-tile; W transposed to LDS (WT[n][k]).
// Fragment layouts per guide (m89/m91-verified): A[m=lane&15][k=quad*8+j],
// B[n=lane&15][k=quad*8+j], D: col=lane&15, row=quad*4+reg.
// ---------------------------------------------------------------------------
#define LSTR 136   // LDS row stride in shorts (16B-aligned, breaks pow2)

__global__ __launch_bounds__(256) void gcn_gemm_mfma(
    const float* __restrict__ x, const float* __restrict__ W,
    const float* __restrict__ bias, ushort* __restrict__ support, int M) {
  __shared__ ushort WT[D * LSTR];      // 34816 B, WT[n][k]
  __shared__ ushort XT[BSPAN * LSTR];  // 17408 B, XT[m][k]; reused for repack

  const int t = threadIdx.x;
  const int w = t >> 6;
  const int lane = t & 63;
  const int quad = lane >> 4;
  const int l16 = lane & 15;
  const int row0 = blockIdx.x * BSPAN;

  // stage W (row-major [k][n] fp32) -> WT[n][k] bf16 (transpose)
  for (int i = t * 4; i < D * D; i += 1024) {
    const int k = i >> 7, n = i & 127;
    const float4 wv = *(const float4*)&W[i];
    WT[(n + 0) * LSTR + k] = f2bf(wv.x);
    WT[(n + 1) * LSTR + k] = f2bf(wv.y);
    WT[(n + 2) * LSTR + k] = f2bf(wv.z);
    WT[(n + 3) * LSTR + k] = f2bf(wv.w);
  }
  // stage x rows -> XT[m][k] bf16 (zero-pad past M)
  for (int i = t * 4; i < BSPAN * D; i += 1024) {
    const int m = i >> 7, k = i & 127;
    const int r = row0 + m;
    float4 xv = make_float4(0.f, 0.f, 0.f, 0.f);
    if (r < M) xv = *(const float4*)&x[(size_t)r * D + k];
    ushort4 pv;
    pv.x = f2bf(xv.x); pv.y = f2bf(xv.y); pv.z = f2bf(xv.z); pv.w = f2bf(xv.w);
    *(ushort4*)&XT[m * LSTR + k] = pv;
  }
  __syncthreads();

  floatx4 acc[8];
#pragma unroll
  for (int nt = 0; nt < 8; nt++) acc[nt] = (floatx4)0.f;

#pragma unroll
  for (int kc = 0; kc < 4; kc++) {
    const short8 a = *(const short8*)&XT[(w * 16 + l16) * LSTR + kc * 32 + quad * 8];
#pragma unroll
    for (int nt = 0; nt < 8; nt++) {
      const short8 b = *(const short8*)&WT[(nt * 16 + l16) * LSTR + kc * 32 + quad * 8];
      acc[nt] = __builtin_amdgcn_mfma_f32_16x16x32_bf16(a, b, acc[nt], 0, 0, 0);
    }
  }

  float bs[8];
#pragma unroll
  for (int nt = 0; nt < 8; nt++) bs[nt] = bias[nt * 16 + l16];

  __syncthreads();  // done reading XT as input tile
  // repack D into XT (row-major, stride LSTR) for coalesced writeout
#pragma unroll
  for (int nt = 0; nt < 8; nt++)
#pragma unroll
    for (int r = 0; r < 4; r++)
      XT[(w * 16 + quad * 4 + r) * LSTR + nt * 16 + l16] = f2bf(acc[nt][r] + bs[nt]);
  __syncthreads();

  for (int i = t * 8; i < BSPAN * D; i += 2048) {
    const int m = i >> 7, k = i & 127;
    const int r = row0 + m;
    if (r < M)
      *(ushort8v*)&support[(size_t)r * D + k] = *(const ushort8v*)&XT[m * LSTR + k];
  }
}

// ---------------------------------------------------------------------------
// Partition: block-local binning -> contiguous per-block runs in row buckets.
// ---------------------------------------------------------------------------
__global__ __launch_bounds__(1024) void partition_kernel(
    const int* __restrict__ erow, const int* __restrict__ ecol,
    const float* __restrict__ eval, int* __restrict__ tails,
    int2* __restrict__ recs, int* __restrict__ ovf_cnt,
    int3* __restrict__ ovf) {
  __shared__ int cnt[NB];
  __shared__ int cursor[NB];
  const int t = threadIdx.x;
  for (int i = t; i < NB; i += 1024) cnt[i] = 0;
  __syncthreads();

  const int e0 = blockIdx.x * PCHUNK;
  for (int e = e0 + t; e < e0 + PCHUNK; e += 1024)
    atomicAdd(&cnt[erow[e] >> 6], 1);
  __syncthreads();

  for (int i = t; i < NB; i += 1024) {
    const int c = cnt[i];
    cursor[i] = (c > 0) ? atomicAdd(&tails[i], c) : 0;
  }
  __syncthreads();

  for (int e = e0 + t; e < e0 + PCHUNK; e += 1024) {
    const int row = erow[e];
    const int b = row >> 6;
    const int pos = atomicAdd(&cursor[b], 1);
    const int col = ecol[e];
    const int vb = __float_as_int(eval[e]);
    if (pos < CAP) {
      recs[(size_t)b * CAP + pos] = make_int2(col | ((row & 63) << 20), vb);
    } else {
      const int oi = atomicAdd(ovf_cnt, 1);
      if (oi < OVF_CAP) ovf[oi] = make_int3(row, col, vb);
    }
  }
}

// ---------------------------------------------------------------------------
// Fused bin+gather: block = one 64-row bucket.
//  1) records cached in registers; bin into per-row order in LDS
//  2) wave w owns rows w*16..+15; HALF-WAVE per record (2 records/iter):
//     lane owns 4 cols (uint2 = 8 B), float4 register acc, halves combined
//     via shfl_xor(32); 512 B row written once by lanes 0-31.
// ---------------------------------------------------------------------------
__global__ __launch_bounds__(256) void bucket_gather(
    const ushort* __restrict__ sup, const int* __restrict__ tails,
    const int2* __restrict__ recs, float* __restrict__ out) {
  __shared__ int2 lrec[CAP];            // 20 KB
  __shared__ int rcnt[BSPAN];
  __shared__ int rstart[BSPAN];
  __shared__ int rend[BSPAN];
  __shared__ int rpos[BSPAN];

  const int bi = blockIdx.x;
  const int t = threadIdx.x;
  const int n = min(tails[bi], CAP);
  const int2* __restrict__ gbase = recs + (size_t)bi * CAP;

  if (t < BSPAN) rcnt[t] = 0;
  __syncthreads();

  // cache this thread's records (<= ceil(CAP/256) = 10)
  int2 rcache[10];
  int nr = 0;
  for (int i = t; i < n; i += 256) rcache[nr++] = gbase[i];

  for (int j = 0; j < nr; j++) atomicAdd(&rcnt[rcache[j].x >> 20], 1);
  __syncthreads();

  if (t < 64) {
    const int c = rcnt[t];
    int v = c;
#pragma unroll
    for (int off = 1; off < 64; off <<= 1) {
      const int u = __shfl_up(v, off);
      if (t >= off) v += u;
    }
    rend[t] = v;
    rstart[t] = v - c;
    rpos[t] = v - c;
  }
  __syncthreads();

  for (int j = 0; j < nr; j++) {
    const int2 rc = rcache[j];
    const int p = atomicAdd(&rpos[rc.x >> 20], 1);
    lrec[p] = make_int2((rc.x & 0xFFFFF) << 8, rc.y);  // byte offset into sup
  }
  __syncthreads();

  const int lane = t & 63;
  const int w = t >> 6;
  const int h = lane >> 5;        // half index: which record of the pair
  const int hl = lane & 31;       // owns cols 4*hl .. 4*hl+3
  const char* __restrict__ supb = (const char*)sup;

  for (int j = 0; j < 16; j++) {
    const int rr = w * 16 + j;
    const int s = rstart[rr];
    const int e = rend[rr];
    float4 acc = make_float4(0.f, 0.f, 0.f, 0.f);
#pragma unroll 2
    for (int i = s; i < e; i += 2) {
      const int idx = i + h;
      const int2 rc = lrec[min(idx, CAP - 1)];
      const bool valid = idx < e;
      const int coff = valid ? rc.x : 0;
      const float val = valid ? __int_as_float(rc.y) : 0.f;
      const uint2 b = *(const uint2*)(supb + coff + hl * 8);
      acc.x += val * bf_lo(b.x);
      acc.y += val * bf_hi(b.x);
      acc.z += val * bf_lo(b.y);
      acc.w += val * bf_hi(b.y);
    }
    acc.x += __shfl_xor(acc.x, 32);
    acc.y += __shfl_xor(acc.y, 32);
    acc.z += __shfl_xor(acc.z, 32);
    acc.w += __shfl_xor(acc.w, 32);
    const int row = bi * BSPAN + rr;
    if (h == 0 && row < N_NODES)
      *(float4*)&out[(size_t)row * D + hl * 4] = acc;
  }
}

// Overflow apply (expected n == 0; formal safety net). Runs AFTER gather.
__global__ __launch_bounds__(256) void ovf_apply(
    const int* __restrict__ ovf_cnt, const int3* __restrict__ ovf,
    const ushort* __restrict__ sup, float* __restrict__ out) {
  const int tid = blockIdx.x * 256 + threadIdx.x;
  const int e = tid >> 5;
  const int n = min(*ovf_cnt, OVF_CAP);
  if (e >= n) return;
  const int3 rec = ovf[e];
  const float val = __int_as_float(rec.z);
  const int j = (tid & 31) * 4;
#pragma unroll
  for (int k = 0; k < 4; k++) {
    const float f = __uint_as_float(((uint)sup[(size_t)rec.y * D + j + k]) << 16);
    unsafeAtomicAdd(&out[(size_t)rec.x * D + j + k], val * f);
  }
}

// Fallback (atomic path, bf16 support) if ws is too small.
__global__ __launch_bounds__(256) void gcn_spmm_atomic(
    const ushort* __restrict__ sup, const float* __restrict__ edge_val,
    const int* __restrict__ edge_row, const int* __restrict__ edge_col,
    float* __restrict__ out) {
  const long long tid = (long long)blockIdx.x * blockDim.x + threadIdx.x;
  const int e = (int)(tid >> 5);
  if (e >= N_EDGES) return;
  const int j = ((int)tid & 31) * 4;
  const int col = edge_col[e];
  const int row = edge_row[e];
  const float val = edge_val[e];
#pragma unroll
  for (int k = 0; k < 4; k++) {
    const float f = __uint_as_float(((uint)sup[(size_t)col * D + j + k]) << 16);
    unsafeAtomicAdd(&out[(size_t)row * D + j + k], val * f);
  }
}

extern "C" void kernel_launch(void* const* d_in, const int* in_sizes, int n_in,
                              void* d_out, int out_size, void* d_ws,
                              size_t ws_size, hipStream_t stream) {
  const float* x        = (const float*)d_in[0];
  const float* edge_val = (const float*)d_in[1];
  const float* W        = (const float*)d_in[2];
  const float* bias     = (const float*)d_in[3];
  const int*   edge_row = (const int*)d_in[4];
  const int*   edge_col = (const int*)d_in[5];
  float* out = (float*)d_out;

  char* ws = (char*)d_ws;
  ushort* support = (ushort*)(ws + SUP_OFF);

  const int gemm_blocks = (N_NODES + BSPAN - 1) / BSPAN;
  gcn_gemm_mfma<<<gemm_blocks, 256, 0, stream>>>(x, W, bias, support, N_NODES);

  if (ws_size >= WS_NEED) {
    int2* recs   = (int2*)(ws + RECS_OFF);
    int*  tails  = (int*)(ws + TAILS_OFF);
    int*  ovfcnt = (int*)(ws + OVFCNT_OFF);
    int3* ovf    = (int3*)(ws + OVF_OFF);

    hipMemsetAsync(tails, 0, (size_t)NB * 4 + 4, stream);
    partition_kernel<<<PBLOCKS, 1024, 0, stream>>>(edge_row, edge_col, edge_val,
                                                   tails, recs, ovfcnt, ovf);
    bucket_gather<<<NB, 256, 0, stream>>>(support, tails, recs, out);
    ovf_apply<<<OVF_CAP * 32 / 256, 256, 0, stream>>>(ovfcnt, ovf, support, out);
  } else {
    hipMemsetAsync(out, 0, (size_t)out_size * sizeof(float), stream);
    const long long spmm_threads = (long long)N_EDGES * 32;
    gcn_spmm_atomic<<<(int)((spmm_threads + 255) / 256), 256, 0, stream>>>(
        support, edge_val, edge_row, edge_col, out);
  }
}